// Round 4
// baseline (22235.695 us; speedup 1.0000x reference)
//
#include <hip/hip_runtime.h>
#include <hip/hip_bf16.h>

// SliceLSTM persistent kernel for gfx950. F32 in/out; MFMA via double-bf16
// 3-term products. 32 blocks x 256 threads; block owns 16 h-columns.
// Cross-block traffic (acts, h, barrier counter) uses agent-scope relaxed
// atomics -> global_load/store sc1 (write/read-through L2 to coherent L3).
// NO threadfence (no buffer_wbl2/buffer_inv cache nukes): barrier is
// s_waitcnt vmcnt(0) + atomicAdd + poll. Read-only streams stay L2-cached.

typedef unsigned short u16;
typedef unsigned long long u64;
typedef __attribute__((ext_vector_type(8))) short short8;
typedef __attribute__((ext_vector_type(4))) float floatx4;

#define NB 32
#define NT 256
#define TSTEPS 512

// ---- workspace layout (bytes) ----
#define WS_CNT 0
#define WS_H_HI 256
#define WS_H_LO (WS_H_HI + 65536)
#define WS_ZERO_BYTES (WS_H_LO + 65536)    // zeroed every call
#define WS_ACT_HI (WS_ZERO_BYTES)
#define WS_ACT_LO (WS_ACT_HI + 262144)
#define WS_W1HI (WS_ACT_LO + 262144)       // 32 blk * 64 row * 192 k * 2B
#define WS_W1LO (WS_W1HI + 786432)
#define WS_W2HI (WS_W1LO + 786432)         // 32 blk * 64 row * 512 k * 2B
#define WS_W2LO (WS_W2HI + 2097152)

__device__ __forceinline__ float b2f(u16 u) {
  unsigned v = ((unsigned)u) << 16;
  float f;
  __builtin_memcpy(&f, &v, 4);
  return f;
}
__device__ __forceinline__ u16 f2b(float f) {
  __hip_bfloat16 h = __float2bfloat16(f);  // RNE
  u16 u;
  __builtin_memcpy(&u, &h, 2);
  return u;
}
__device__ __forceinline__ float sigf(float x) { return 1.0f / (1.0f + __expf(-x)); }
__device__ __forceinline__ float tanhf_fast(float x) { return 2.0f * sigf(2.0f * x) - 1.0f; }
__device__ __forceinline__ short8 ld8(const u16* p) { return *(const short8*)p; }

// device-coherent (sc1) 16B fragment load: two relaxed agent-scope u64 atomics
__device__ __forceinline__ short8 lda_frag(const u16* p) {
  union {
    u64 q[2];
    short8 s;
  } u;
  u.q[0] = __hip_atomic_load((const u64*)p, __ATOMIC_RELAXED, __HIP_MEMORY_SCOPE_AGENT);
  u.q[1] = __hip_atomic_load((const u64*)(p + 4), __ATOMIC_RELAXED, __HIP_MEMORY_SCOPE_AGENT);
  return u.s;
}
// device-coherent (sc1) 2B store
__device__ __forceinline__ void sta16(u16* p, u16 v) {
  __hip_atomic_store(p, v, __ATOMIC_RELAXED, __HIP_MEMORY_SCOPE_AGENT);
}

__device__ __forceinline__ void split8(const float* p, short8& hi, short8& lo) {
  float4 a = *(const float4*)p;
  float4 b = *(const float4*)(p + 4);
  float v[8] = {a.x, a.y, a.z, a.w, b.x, b.y, b.z, b.w};
#pragma unroll
  for (int i = 0; i < 8; ++i) {
    u16 h = f2b(v[i]);
    hi[i] = (short)h;
    lo[i] = (short)f2b(v[i] - b2f(h));
  }
}

// No cache-flush fences: all cross-block data moved with sc1 ops, so draining
// vmcnt to the coherence point is the complete release action.
__device__ __forceinline__ void grid_barrier(unsigned* cnt, unsigned target) {
  asm volatile("s_waitcnt vmcnt(0)" ::: "memory");
  __syncthreads();
  if (threadIdx.x == 0) {
    __hip_atomic_fetch_add(cnt, 1u, __ATOMIC_RELAXED, __HIP_MEMORY_SCOPE_AGENT);
    while (__hip_atomic_load(cnt, __ATOMIC_RELAXED, __HIP_MEMORY_SCOPE_AGENT) < target)
      __builtin_amdgcn_s_sleep(1);
  }
  __syncthreads();
}

__global__ void __launch_bounds__(NT) init_ws_kernel(unsigned* w, int n) {
  int i = blockIdx.x * blockDim.x + threadIdx.x;
  const int st = gridDim.x * blockDim.x;
  for (; i < n; i += st) w[i] = 0u;
}

// split Ws/Us (f32) into per-block k-contiguous bf16 hi/lo tiles
__global__ void __launch_bounds__(NT) prep_w1_kernel(const float* __restrict__ Ws,
                                                     const float* __restrict__ Us,
                                                     u16* __restrict__ w1hi,
                                                     u16* __restrict__ w1lo) {
  const int idx = blockIdx.x * NT + threadIdx.x;  // < 4*192*512
  const int c = idx & 511;
  const int rest = idx >> 9;
  const int k = rest % 192;
  const int s = rest / 192;
  const float w = (k < 64) ? Ws[(size_t)(s * 64 + k) * 512 + c]
                           : Us[(size_t)(s * 128 + (k - 64)) * 512 + c];
  const u16 hi = f2b(w);
  const u16 lo = f2b(w - b2f(hi));
  const int g = c >> 7, cs = c & 127;
  const int blk = s * 8 + (cs >> 4), jj = cs & 15;
  const int dst = blk * 12288 + (g * 16 + jj) * 192 + k;
  w1hi[dst] = hi;
  w1lo[dst] = lo;
}

// split Wc (f32, [k=512][j=2048]) into per-block k-contiguous bf16 hi/lo
__global__ void __launch_bounds__(NT) prep_w2_kernel(const float* __restrict__ Wc,
                                                     u16* __restrict__ w2hi,
                                                     u16* __restrict__ w2lo) {
  __shared__ u16 th[256 * 40];
  __shared__ u16 tl[256 * 40];
  const int tid = threadIdx.x;
  const int k0 = (blockIdx.x >> 3) * 32;
  const int j0 = (blockIdx.x & 7) * 256;
#pragma unroll 4
  for (int i = 0; i < 32; ++i) {
    const float w = Wc[(size_t)(k0 + i) * 2048 + j0 + tid];
    const u16 hi = f2b(w);
    th[tid * 40 + i] = hi;
    tl[tid * 40 + i] = f2b(w - b2f(hi));
  }
  __syncthreads();
  const int j = j0 + tid;
  const int blk = (j & 511) >> 4, g = j >> 9, jj = j & 15;
  u16* dh = w2hi + blk * 32768 + (g * 16 + jj) * 512 + k0;
  u16* dl = w2lo + blk * 32768 + (g * 16 + jj) * 512 + k0;
#pragma unroll
  for (int q = 0; q < 4; ++q) {
    *(uint4*)(dh + q * 8) = *(const uint4*)&th[tid * 40 + q * 8];
    *(uint4*)(dl + q * 8) = *(const uint4*)&tl[tid * 40 + q * 8];
  }
}

__global__ void __launch_bounds__(NT) slicelstm_kernel(
    const float* __restrict__ x, const float* __restrict__ biases,
    const float* __restrict__ bcg, float* __restrict__ out,
    const u16* __restrict__ w1hi, const u16* __restrict__ w1lo,
    const u16* __restrict__ w2hi, const u16* __restrict__ w2lo,
    u16* __restrict__ act_hi, u16* __restrict__ act_lo,
    u16* __restrict__ h_hi, u16* __restrict__ h_lo,
    unsigned* __restrict__ cnt) {
  __shared__ __align__(16) u16 W1H[64 * 200];  // [row=g*16+jj][k 0..191] (+8 pad)
  __shared__ __align__(16) u16 W1L[64 * 200];
  __shared__ __align__(16) u16 W2H[64 * 520];  // [row=g*16+jj][k 0..511] (+8 pad)

  const int tid = threadIdx.x;
  const int blk = blockIdx.x;
  const int j0 = blk * 16;
  const int s = j0 >> 7;
  const int jbase = j0 & 127;

  // ---- one-time: stage prepped weights into LDS (plain loads, L2-cached) ----
  {
    const u16* s1h = w1hi + blk * 12288;
    const u16* s1l = w1lo + blk * 12288;
    for (int i = tid; i < 64 * 24; i += NT) {
      const int r = i / 24, ck = i % 24;
      *(uint4*)&W1H[r * 200 + ck * 8] = *(const uint4*)&s1h[r * 192 + ck * 8];
      *(uint4*)&W1L[r * 200 + ck * 8] = *(const uint4*)&s1l[r * 192 + ck * 8];
    }
    const u16* s2h = w2hi + blk * 32768;
    for (int i = tid; i < 64 * 64; i += NT) {
      const int r = i >> 6, ck = i & 63;
      *(uint4*)&W2H[r * 520 + ck * 8] = *(const uint4*)&s2h[r * 512 + ck * 8];
    }
  }
  __syncthreads();

  const int lane = tid & 63;
  const int mt = tid >> 6;        // wave id = M-tile (16 batch rows)
  const int lm = lane & 15;
  const int lq = lane >> 4;
  const int ko = lq * 8;          // fragment k offset: k = quad*8 + j
  const int arow = mt * 16 + lm;  // A-operand row (batch)

  float biasv[4], bcv[4];
#pragma unroll
  for (int g = 0; g < 4; ++g) {
    biasv[g] = biases[s * 512 + g * 128 + jbase + lm];
    bcv[g] = bcg[g * 512 + j0 + lm];
  }

  const u16 *p1h[4], *p1l[4], *p2h[4], *p2l[4], *ahr[4], *alr[4];
#pragma unroll
  for (int g = 0; g < 4; ++g) {
    p1h[g] = &W1H[(g * 16 + lm) * 200];
    p1l[g] = &W1L[(g * 16 + lm) * 200];
    p2h[g] = &W2H[(g * 16 + lm) * 520];
    p2l[g] = w2lo + blk * 32768 + (g * 16 + lm) * 512;  // plain, L2-resident
    ahr[g] = act_hi + (g * 64 + arow) * 512;
    alr[g] = act_lo + (g * 64 + arow) * 512;
  }
  const float* xrow = x + (size_t)arow * 512 * 256 + s * 64;
  const int hbase = arow * 512 + s * 128;

  float creg[4] = {0.f, 0.f, 0.f, 0.f};  // cell state lives in registers
  unsigned epoch = 0;

  for (int t = 0; t < TSTEPS; ++t) {
    // ---- phase 0: A-fragments for stage 1 (x plain; h via sc1) ----
    short8 xh[2], xl[2], hh[4], hl[4];
    {
      const float* xp = xrow + t * 256;
#pragma unroll
      for (int kt = 0; kt < 2; ++kt) split8(xp + kt * 32 + ko, xh[kt], xl[kt]);
#pragma unroll
      for (int kt = 0; kt < 4; ++kt) {
        hh[kt] = lda_frag(&h_hi[hbase + kt * 32 + ko]);
        hl[kt] = lda_frag(&h_lo[hbase + kt * 32 + ko]);
      }
    }

    // ---- phase 1: block-diag gates + activations -> act bufs (sc1) ----
#pragma unroll
    for (int g = 0; g < 4; ++g) {
      floatx4 acc = {0.f, 0.f, 0.f, 0.f};
#pragma unroll
      for (int kt = 0; kt < 2; ++kt) {
        const short8 bh = ld8(p1h[g] + kt * 32 + ko);
        const short8 bl = ld8(p1l[g] + kt * 32 + ko);
        acc = __builtin_amdgcn_mfma_f32_16x16x32_bf16(xh[kt], bh, acc, 0, 0, 0);
        acc = __builtin_amdgcn_mfma_f32_16x16x32_bf16(xl[kt], bh, acc, 0, 0, 0);
        acc = __builtin_amdgcn_mfma_f32_16x16x32_bf16(xh[kt], bl, acc, 0, 0, 0);
      }
#pragma unroll
      for (int kt = 0; kt < 4; ++kt) {
        const short8 bh = ld8(p1h[g] + 64 + kt * 32 + ko);
        const short8 bl = ld8(p1l[g] + 64 + kt * 32 + ko);
        acc = __builtin_amdgcn_mfma_f32_16x16x32_bf16(hh[kt], bh, acc, 0, 0, 0);
        acc = __builtin_amdgcn_mfma_f32_16x16x32_bf16(hl[kt], bh, acc, 0, 0, 0);
        acc = __builtin_amdgcn_mfma_f32_16x16x32_bf16(hh[kt], bl, acc, 0, 0, 0);
      }
#pragma unroll
      for (int r = 0; r < 4; ++r) {  // C/D: col = lane&15, row = (lane>>4)*4 + r
        const int brow = mt * 16 + lq * 4 + r;
        const float pre = acc[r] + biasv[g];
        const float a = (g == 2) ? tanhf_fast(pre) : sigf(pre);
        const u16 ah = f2b(a);
        const int o = (g * 64 + brow) * 512 + j0 + lm;
        sta16(&act_hi[o], ah);
        sta16(&act_lo[o], f2b(a - b2f(ah)));
      }
    }
    epoch++;
    grid_barrier(cnt, epoch * NB);

    // ---- phase 2: connector GEMM (acts via sc1; W2 hi LDS, lo L2) ----
    floatx4 acc2[4];
#pragma unroll
    for (int g = 0; g < 4; ++g) acc2[g] = (floatx4){0.f, 0.f, 0.f, 0.f};
#pragma unroll 4
    for (int kt = 0; kt < 16; ++kt) {
      const int kb = kt * 32 + ko;
#pragma unroll
      for (int g = 0; g < 4; ++g) {
        const short8 Ah = lda_frag(ahr[g] + kb);
        const short8 Al = lda_frag(alr[g] + kb);
        const short8 Bh = ld8(p2h[g] + kb);  // LDS
        const short8 Bl = ld8(p2l[g] + kb);  // global, L2-resident
        acc2[g] = __builtin_amdgcn_mfma_f32_16x16x32_bf16(Ah, Bh, acc2[g], 0, 0, 0);
        acc2[g] = __builtin_amdgcn_mfma_f32_16x16x32_bf16(Al, Bh, acc2[g], 0, 0, 0);
        acc2[g] = __builtin_amdgcn_mfma_f32_16x16x32_bf16(Ah, Bl, acc2[g], 0, 0, 0);
      }
    }

    // ---- phase 3: elementwise LSTM update (c in registers) ----
    {
      const int j = j0 + lm;
#pragma unroll
      for (int r = 0; r < 4; ++r) {
        const int brow = mt * 16 + lq * 4 + r;
        const float it = sigf(acc2[0][r] + bcv[0]);
        const float ft = sigf(acc2[1][r] + bcv[1]);
        const float gt = tanhf_fast(acc2[2][r] + bcv[2]);
        const float ot = sigf(acc2[3][r] + bcv[3]);
        const float cn = ft * creg[r] + it * gt;
        creg[r] = cn;
        const float h = ot * tanhf_fast(cn);
        const int ci = brow * 512 + j;
        const u16 hh2 = f2b(h);
        sta16(&h_hi[ci], hh2);
        sta16(&h_lo[ci], f2b(h - b2f(hh2)));
        out[((size_t)(brow * TSTEPS + t)) * 512 + j] = h;  // hidden_seq f32
        if (t == TSTEPS - 1) {
          out[16777216 + ci] = h;           // final h_t
          out[16777216 + 32768 + ci] = cn;  // final c_t
        }
      }
    }
    epoch++;
    grid_barrier(cnt, epoch * NB);
  }
}

extern "C" void kernel_launch(void* const* d_in, const int* in_sizes, int n_in,
                              void* d_out, int out_size, void* d_ws, size_t ws_size,
                              hipStream_t stream) {
  const float* x = (const float*)d_in[0];
  const float* Ws = (const float*)d_in[1];
  const float* Us = (const float*)d_in[2];
  const float* biases = (const float*)d_in[3];
  const float* Wc = (const float*)d_in[4];
  const float* bc = (const float*)d_in[5];

  char* ws = (char*)d_ws;
  unsigned* cnt = (unsigned*)(ws + WS_CNT);
  u16* h_hi = (u16*)(ws + WS_H_HI);
  u16* h_lo = (u16*)(ws + WS_H_LO);
  u16* act_hi = (u16*)(ws + WS_ACT_HI);
  u16* act_lo = (u16*)(ws + WS_ACT_LO);
  u16* w1hi = (u16*)(ws + WS_W1HI);
  u16* w1lo = (u16*)(ws + WS_W1LO);
  u16* w2hi = (u16*)(ws + WS_W2HI);
  u16* w2lo = (u16*)(ws + WS_W2LO);

  hipLaunchKernelGGL(init_ws_kernel, dim3(64), dim3(NT), 0, stream, (unsigned*)ws,
                     WS_ZERO_BYTES / 4);
  hipLaunchKernelGGL(prep_w1_kernel, dim3(1536), dim3(NT), 0, stream, Ws, Us, w1hi, w1lo);
  hipLaunchKernelGGL(prep_w2_kernel, dim3(128), dim3(NT), 0, stream, Wc, w2hi, w2lo);
  hipLaunchKernelGGL(slicelstm_kernel, dim3(NB), dim3(NT), 0, stream, x, biases, bc,
                     (float*)d_out, w1hi, w1lo, w2hi, w2lo, act_hi, act_lo, h_hi, h_lo,
                     cnt);
}

// Round 5
// 8140.163 us; speedup vs baseline: 2.7316x; 2.7316x over previous
//
#include <hip/hip_runtime.h>
#include <hip/hip_bf16.h>

// SliceLSTM persistent kernel for gfx950, round 5.
// Batch rows are independent => 4 independent quarters (16 b each) x 32
// j-tiles = 128 blocks x 256 thr. Wave = gate. Weight hi-planes in LDS,
// lo-planes in VGPRs (immune to L2 inv). Acts/h: sc1 write-through stores,
// PLAIN loads + acquire-fence (buffer_inv, no wbl2) in the 32-wide
// per-quarter grid barrier (2/step). c lives in 1 register/thread.

typedef unsigned short u16;
typedef __attribute__((ext_vector_type(8))) short short8;
typedef __attribute__((ext_vector_type(4))) float floatx4;

#define NT 256
#define NBLK 128
#define NBQ 32  // blocks per quarter (barrier width)
#define TSTEPS 512

// ---- workspace layout (bytes) ----
#define WS_CNT 0                         // 4 counters, 128 B apart
#define WS_H_HI 1024                     // 64 b x 512 j u16
#define WS_H_LO (WS_H_HI + 65536)
#define WS_ZERO_BYTES (WS_H_LO + 65536)  // zeroed every call
#define WS_ACT_HI (WS_ZERO_BYTES)        // [4 g][64 b][512 k] u16
#define WS_ACT_LO (WS_ACT_HI + 262144)
#define WS_END (WS_ACT_LO + 262144)      // ~645 KB total

__device__ __forceinline__ float b2f(u16 u) {
  unsigned v = ((unsigned)u) << 16;
  float f;
  __builtin_memcpy(&f, &v, 4);
  return f;
}
__device__ __forceinline__ u16 f2b(float f) {
  __hip_bfloat16 h = __float2bfloat16(f);  // RNE
  u16 u;
  __builtin_memcpy(&u, &h, 2);
  return u;
}
__device__ __forceinline__ float sigf(float x) { return 1.0f / (1.0f + __expf(-x)); }
__device__ __forceinline__ float tanhf_fast(float x) { return 2.0f * sigf(2.0f * x) - 1.0f; }
__device__ __forceinline__ short8 ld8(const u16* p) { return *(const short8*)p; }

// device-coherent (sc1) 2B store: write-through to L3
__device__ __forceinline__ void sta16(u16* p, u16 v) {
  __hip_atomic_store(p, v, __ATOMIC_RELAXED, __HIP_MEMORY_SCOPE_AGENT);
}

__device__ __forceinline__ void split8(const float* p, short8& hi, short8& lo) {
  float4 a = *(const float4*)p;
  float4 b = *(const float4*)(p + 4);
  float v[8] = {a.x, a.y, a.z, a.w, b.x, b.y, b.z, b.w};
#pragma unroll
  for (int i = 0; i < 8; ++i) {
    u16 h = f2b(v[i]);
    hi[i] = (short)h;
    lo[i] = (short)f2b(v[i] - b2f(h));
  }
}

// Release: sc1 stores are acked at the coherent point when vmcnt drains.
// Acquire: buffer_inv (no L2 writeback) so PLAIN loads refill fresh from L3.
__device__ __forceinline__ void grid_barrier(unsigned* cnt, unsigned target) {
  asm volatile("s_waitcnt vmcnt(0)" ::: "memory");
  __syncthreads();
  if (threadIdx.x == 0) {
    __hip_atomic_fetch_add(cnt, 1u, __ATOMIC_RELAXED, __HIP_MEMORY_SCOPE_AGENT);
    while (__hip_atomic_load(cnt, __ATOMIC_RELAXED, __HIP_MEMORY_SCOPE_AGENT) < target)
      __builtin_amdgcn_s_sleep(1);
  }
  __syncthreads();
  __builtin_amdgcn_fence(__ATOMIC_ACQUIRE, "agent");
}

__global__ void __launch_bounds__(NT) init_ws_kernel(unsigned* w, int n) {
  int i = blockIdx.x * blockDim.x + threadIdx.x;
  const int st = gridDim.x * blockDim.x;
  for (; i < n; i += st) w[i] = 0u;
}

__global__ void __launch_bounds__(NT, 1) slicelstm_kernel(
    const float* __restrict__ x, const float* __restrict__ Ws,
    const float* __restrict__ Us, const float* __restrict__ biases,
    const float* __restrict__ Wc, const float* __restrict__ bcg,
    float* __restrict__ out, u16* __restrict__ act_hi, u16* __restrict__ act_lo,
    u16* __restrict__ h_hi, u16* __restrict__ h_lo, unsigned* __restrict__ cntbase) {
  __shared__ __align__(16) u16 W1H[64 * 200];   // [row=g*16+jj][k 0..191] +8 pad
  __shared__ __align__(16) u16 W2H[64 * 520];   // [row=g*16+jj][k 0..511] +8 pad
  __shared__ float gx[4][16][17];               // gate-exchange, +1 pad

  const int tid = threadIdx.x;
  const int blk = blockIdx.x;
  const int q = blk & 3;        // batch quarter (constant per XCD: blk%8 fixes blk&3)
  const int jt = blk >> 2;      // j-tile 0..31
  const int j0 = jt * 16;
  const int s = j0 >> 7;        // slice
  const int jbase = j0 & 127;
  unsigned* cnt = cntbase + q * 32;  // 128 B apart

  // ---- one-time: split f32 weights, hi-planes -> LDS ----
  for (int i = tid; i < 64 * 192; i += NT) {
    const int r = i / 192, k = i % 192;
    const int col = (r >> 4) * 128 + jbase + (r & 15);  // gate*128 + j within slice
    const float w = (k < 64) ? Ws[(size_t)(s * 64 + k) * 512 + col]
                             : Us[(size_t)(s * 128 + (k - 64)) * 512 + col];
    W1H[r * 200 + k] = f2b(w);
  }
  for (int i = tid; i < 64 * 512; i += NT) {
    const int r = i >> 9, k = i & 511;
    const int col = (r >> 4) * 512 + j0 + (r & 15);
    W2H[r * 520 + k] = f2b(Wc[(size_t)k * 2048 + col]);
  }

  const int lane = tid & 63;
  const int g = tid >> 6;   // wave id = GATE (0=i,1=f,2=g,3=o)
  const int lm = lane & 15; // fragment col (j) / A-row (b)
  const int lq = lane >> 4;
  const int ko = lq * 8;    // fragment k offset: k = quad*8 + e

  // ---- one-time: lo-plane fragments -> VGPRs (immune to L2 inv) ----
  short8 w1l[6], w2l[16];
#pragma unroll
  for (int kt = 0; kt < 6; ++kt) {
    const int col = (g << 7) + jbase + lm;
#pragma unroll
    for (int e = 0; e < 8; ++e) {
      const int k = kt * 32 + ko + e;
      const float w = (k < 64) ? Ws[(size_t)(s * 64 + k) * 512 + col]
                               : Us[(size_t)(s * 128 + (k - 64)) * 512 + col];
      w1l[kt][e] = (short)f2b(w - b2f(f2b(w)));
    }
  }
#pragma unroll
  for (int kt = 0; kt < 16; ++kt) {
    const int col = (g << 9) + j0 + lm;
#pragma unroll
    for (int e = 0; e < 8; ++e) {
      const int k = kt * 32 + ko + e;
      const float w = Wc[(size_t)k * 2048 + col];
      w2l[kt][e] = (short)f2b(w - b2f(f2b(w)));
    }
  }
  const float biasv = biases[s * 512 + (g << 7) + jbase + lm];
  const float bcv = bcg[(g << 9) + j0 + lm];
  __syncthreads();

  const u16* w1r = &W1H[((g << 4) + lm) * 200];
  const u16* w2r = &W2H[((g << 4) + lm) * 520];
  const int brow = q * 16 + lm;                         // A-operand batch row
  const float* xrow = x + (size_t)brow * (512 * 256) + s * 64;
  const int hbase = brow * 512 + s * 128;
  const u16* ahr = act_hi + ((g << 6) + brow) * 512;
  const u16* alr = act_lo + ((g << 6) + brow) * 512;

  // phase-3 thread mapping (b-local, j-local)
  const int p3b = tid >> 4, p3j = tid & 15;
  const int p3ci = (q * 16 + p3b) * 512 + j0 + p3j;
  float creg = 0.f;  // cell state: one register per thread

  unsigned epoch = 0;

  for (int t = 0; t < TSTEPS; ++t) {
    // ---- phase 0: A-fragments (x f32 split, h hi/lo plain loads) ----
    short8 xh[2], xl[2], hh[4], hl[4];
    {
      const float* xp = xrow + t * 256;
#pragma unroll
      for (int kt = 0; kt < 2; ++kt) split8(xp + kt * 32 + ko, xh[kt], xl[kt]);
#pragma unroll
      for (int kt = 0; kt < 4; ++kt) {
        hh[kt] = ld8(&h_hi[hbase + kt * 32 + ko]);
        hl[kt] = ld8(&h_lo[hbase + kt * 32 + ko]);
      }
    }

    // ---- phase 1: stage-1 gates (this wave's gate) -> act bufs (sc1) ----
    {
      floatx4 acc = {0.f, 0.f, 0.f, 0.f};
#pragma unroll
      for (int kt = 0; kt < 2; ++kt) {
        const short8 bh = ld8(w1r + kt * 32 + ko);
        acc = __builtin_amdgcn_mfma_f32_16x16x32_bf16(xh[kt], bh, acc, 0, 0, 0);
        acc = __builtin_amdgcn_mfma_f32_16x16x32_bf16(xl[kt], bh, acc, 0, 0, 0);
        acc = __builtin_amdgcn_mfma_f32_16x16x32_bf16(xh[kt], w1l[kt], acc, 0, 0, 0);
      }
#pragma unroll
      for (int kt = 0; kt < 4; ++kt) {
        const short8 bh = ld8(w1r + 64 + kt * 32 + ko);
        acc = __builtin_amdgcn_mfma_f32_16x16x32_bf16(hh[kt], bh, acc, 0, 0, 0);
        acc = __builtin_amdgcn_mfma_f32_16x16x32_bf16(hl[kt], bh, acc, 0, 0, 0);
        acc = __builtin_amdgcn_mfma_f32_16x16x32_bf16(hh[kt], w1l[2 + kt], acc, 0, 0, 0);
      }
#pragma unroll
      for (int r = 0; r < 4; ++r) {  // C/D: col=lane&15, row=lq*4+r
        const int b = q * 16 + lq * 4 + r;
        const float pre = acc[r] + biasv;
        const float a = (g == 2) ? tanhf_fast(pre) : sigf(pre);
        const u16 ah = f2b(a);
        const int o = ((g << 6) + b) * 512 + j0 + lm;
        sta16(&act_hi[o], ah);
        sta16(&act_lo[o], f2b(a - b2f(ah)));
      }
    }
    epoch++;
    grid_barrier(cnt, epoch * NBQ);

    // ---- phase 2: connector GEMM for this wave's gate (plain act loads) ----
    floatx4 acc2 = {0.f, 0.f, 0.f, 0.f};
#pragma unroll
    for (int kt = 0; kt < 16; ++kt) {
      const int kb = kt * 32 + ko;
      const short8 Ah = ld8(ahr + kb);
      const short8 Al = ld8(alr + kb);
      const short8 Bh = ld8(w2r + kb);
      acc2 = __builtin_amdgcn_mfma_f32_16x16x32_bf16(Ah, Bh, acc2, 0, 0, 0);
      acc2 = __builtin_amdgcn_mfma_f32_16x16x32_bf16(Al, Bh, acc2, 0, 0, 0);
      acc2 = __builtin_amdgcn_mfma_f32_16x16x32_bf16(Ah, w2l[kt], acc2, 0, 0, 0);
    }
#pragma unroll
    for (int r = 0; r < 4; ++r) gx[g][lq * 4 + r][lm] = acc2[r] + bcv;
    __syncthreads();

    // ---- phase 3: elementwise update, thread <-> (b,j) fixed; c in reg ----
    {
      const float it = sigf(gx[0][p3b][p3j]);
      const float ft = sigf(gx[1][p3b][p3j]);
      const float gt = tanhf_fast(gx[2][p3b][p3j]);
      const float ot = sigf(gx[3][p3b][p3j]);
      const float cn = ft * creg + it * gt;
      creg = cn;
      const float h = ot * tanhf_fast(cn);
      const u16 hh2 = f2b(h);
      sta16(&h_hi[p3ci], hh2);
      sta16(&h_lo[p3ci], f2b(h - b2f(hh2)));
      const size_t oi = ((size_t)((q * 16 + p3b) * TSTEPS + t)) * 512 + j0 + p3j;
      __builtin_nontemporal_store(h, &out[oi]);  // hidden_seq, bypass L2
      if (t == TSTEPS - 1) {
        __builtin_nontemporal_store(h, &out[16777216 + p3ci]);        // h_t
        __builtin_nontemporal_store(cn, &out[16777216 + 32768 + p3ci]);  // c_t
      }
    }
    epoch++;
    grid_barrier(cnt, epoch * NBQ);
  }
}

extern "C" void kernel_launch(void* const* d_in, const int* in_sizes, int n_in,
                              void* d_out, int out_size, void* d_ws, size_t ws_size,
                              hipStream_t stream) {
  const float* x = (const float*)d_in[0];
  const float* Ws = (const float*)d_in[1];
  const float* Us = (const float*)d_in[2];
  const float* biases = (const float*)d_in[3];
  const float* Wc = (const float*)d_in[4];
  const float* bc = (const float*)d_in[5];

  char* ws = (char*)d_ws;
  unsigned* cnt = (unsigned*)(ws + WS_CNT);
  u16* h_hi = (u16*)(ws + WS_H_HI);
  u16* h_lo = (u16*)(ws + WS_H_LO);
  u16* act_hi = (u16*)(ws + WS_ACT_HI);
  u16* act_lo = (u16*)(ws + WS_ACT_LO);

  hipLaunchKernelGGL(init_ws_kernel, dim3(64), dim3(NT), 0, stream, (unsigned*)ws,
                     WS_ZERO_BYTES / 4);
  hipLaunchKernelGGL(slicelstm_kernel, dim3(NBLK), dim3(NT), 0, stream, x, Ws, Us,
                     biases, Wc, bc, (float*)d_out, act_hi, act_lo, h_hi, h_lo, cnt);
}

// Round 6
// 6744.678 us; speedup vs baseline: 3.2968x; 1.2069x over previous
//
#include <hip/hip_runtime.h>
#include <hip/hip_bf16.h>

// SliceLSTM persistent kernel for gfx950, round 6.
// 128 blocks x 256 thr: 4 batch quarters x 32 j-tiles; wave = gate.
// Weight hi-planes in LDS, lo-planes in VGPRs. Cross-block data via sc1
// write-through stores + relaxed agent atomic loads (L3), NO cache inv.
// Flag-based barriers (no RMW contention): barrier1 = 32-wide (acts,
// ping-pong buffered), barrier2 = 8-wide slice group (h exchange).
// hidden_seq stores deferred one step; x prefetched during phase 2.

typedef unsigned short u16;
typedef unsigned long long u64;
typedef __attribute__((ext_vector_type(8))) short short8;
typedef __attribute__((ext_vector_type(4))) float floatx4;

#define NT 256
#define NBLK 128
#define TSTEPS 512

// ---- workspace layout (bytes) ----
#define WS_FLAG1 0                        // 4 quarters x 32 u32 (256 B stride)
#define WS_FLAG2 1024                     // 16 groups x 8 u32 (64 B stride)
#define WS_H_HI 2048                      // 64 b x 512 j u16
#define WS_H_LO (WS_H_HI + 65536)
#define WS_ZERO_BYTES (WS_H_LO + 65536)   // zeroed every call
#define WS_ACT_HI (WS_ZERO_BYTES)         // 2 planes x [4g][64b][512k] u16
#define WS_ACT_LO (WS_ACT_HI + 2 * 262144)
#define ACT_PLANE 131072                  // elements per plane

__device__ __forceinline__ float b2f(u16 u) {
  unsigned v = ((unsigned)u) << 16;
  float f;
  __builtin_memcpy(&f, &v, 4);
  return f;
}
__device__ __forceinline__ u16 f2b(float f) {
  __hip_bfloat16 h = __float2bfloat16(f);  // RNE
  u16 u;
  __builtin_memcpy(&u, &h, 2);
  return u;
}
__device__ __forceinline__ float sigf(float x) { return 1.0f / (1.0f + __expf(-x)); }
__device__ __forceinline__ float tanhf_fast(float x) { return 2.0f * sigf(2.0f * x) - 1.0f; }
__device__ __forceinline__ short8 ld8(const u16* p) { return *(const short8*)p; }

// coherent 16B fragment load (sc1, straight from L3; relaxed -> batchable)
__device__ __forceinline__ short8 lda_frag(const u16* p) {
  union {
    u64 q[2];
    short8 s;
  } u;
  u.q[0] = __hip_atomic_load((const u64*)p, __ATOMIC_RELAXED, __HIP_MEMORY_SCOPE_AGENT);
  u.q[1] = __hip_atomic_load((const u64*)(p + 4), __ATOMIC_RELAXED, __HIP_MEMORY_SCOPE_AGENT);
  return u.s;
}
__device__ __forceinline__ void sta16(u16* p, u16 v) {
  __hip_atomic_store(p, v, __ATOMIC_RELAXED, __HIP_MEMORY_SCOPE_AGENT);
}

__device__ __forceinline__ void split8v(float4 a, float4 b, short8& hi, short8& lo) {
  float v[8] = {a.x, a.y, a.z, a.w, b.x, b.y, b.z, b.w};
#pragma unroll
  for (int i = 0; i < 8; ++i) {
    u16 h = f2b(v[i]);
    hi[i] = (short)h;
    lo[i] = (short)f2b(v[i] - b2f(h));
  }
}

// Flag barrier: arrival = sc1 store to own dword (no RMW contention);
// wave 0 polls all flags in one vector load + ballot. No cache maintenance.
__device__ __forceinline__ void barrier_flags(unsigned* flags, int nmask, int myidx,
                                              unsigned target) {
  asm volatile("s_waitcnt vmcnt(0)" ::: "memory");
  __syncthreads();
  const int tid = threadIdx.x;
  if (tid == 0)
    __hip_atomic_store(&flags[myidx], target, __ATOMIC_RELAXED, __HIP_MEMORY_SCOPE_AGENT);
  if (tid < 64) {
    const int fi = tid & nmask;
    for (;;) {
      const unsigned v =
          __hip_atomic_load(&flags[fi], __ATOMIC_RELAXED, __HIP_MEMORY_SCOPE_AGENT);
      if (__ballot(v >= target) == ~0ULL) break;
      __builtin_amdgcn_s_sleep(1);
    }
  }
  __syncthreads();
}

__global__ void __launch_bounds__(NT) init_ws_kernel(unsigned* w, int n) {
  int i = blockIdx.x * blockDim.x + threadIdx.x;
  const int st = gridDim.x * blockDim.x;
  for (; i < n; i += st) w[i] = 0u;
}

__global__ void __launch_bounds__(NT, 1) slicelstm_kernel(
    const float* __restrict__ x, const float* __restrict__ Ws,
    const float* __restrict__ Us, const float* __restrict__ biases,
    const float* __restrict__ Wc, const float* __restrict__ bcg,
    float* __restrict__ out, u16* __restrict__ act_hi, u16* __restrict__ act_lo,
    u16* __restrict__ h_hi, u16* __restrict__ h_lo, unsigned* __restrict__ flagbase) {
  __shared__ __align__(16) u16 W1H[64 * 200];  // [row=g*16+jj][k 0..191] +8 pad
  __shared__ __align__(16) u16 W2H[64 * 520];  // [row=g*16+jj][k 0..511] +8 pad
  __shared__ float gx[4][16][17];              // gate exchange, +1 pad

  const int tid = threadIdx.x;
  const int blk = blockIdx.x;
  const int q = blk & 3;    // batch quarter
  const int jt = blk >> 2;  // j-tile 0..31
  const int j0 = jt * 16;
  const int s = j0 >> 7;    // slice 0..3
  const int jbase = j0 & 127;
  unsigned* flags1 = flagbase + q * 64;                        // 32 flags
  unsigned* flags2 = flagbase + 256 + (q * 4 + s) * 16;        // 8 flags

  // ---- one-time: split f32 weights, hi-planes -> LDS ----
  for (int i = tid; i < 64 * 192; i += NT) {
    const int r = i / 192, k = i % 192;
    const int col = (r >> 4) * 128 + jbase + (r & 15);
    const float w = (k < 64) ? Ws[(size_t)(s * 64 + k) * 512 + col]
                             : Us[(size_t)(s * 128 + (k - 64)) * 512 + col];
    W1H[r * 200 + k] = f2b(w);
  }
  for (int i = tid; i < 64 * 512; i += NT) {
    const int r = i >> 9, k = i & 511;
    const int col = (r >> 4) * 512 + j0 + (r & 15);
    W2H[r * 520 + k] = f2b(Wc[(size_t)k * 2048 + col]);
  }

  const int lane = tid & 63;
  const int g = tid >> 6;   // wave = gate
  const int lm = lane & 15;
  const int lq = lane >> 4;
  const int ko = lq * 8;

  // ---- one-time: lo-plane fragments -> VGPRs ----
  short8 w1l[6], w2l[16];
#pragma unroll
  for (int kt = 0; kt < 6; ++kt) {
    const int col = (g << 7) + jbase + lm;
#pragma unroll
    for (int e = 0; e < 8; ++e) {
      const int k = kt * 32 + ko + e;
      const float w = (k < 64) ? Ws[(size_t)(s * 64 + k) * 512 + col]
                               : Us[(size_t)(s * 128 + (k - 64)) * 512 + col];
      w1l[kt][e] = (short)f2b(w - b2f(f2b(w)));
    }
  }
#pragma unroll
  for (int kt = 0; kt < 16; ++kt) {
    const int col = (g << 9) + j0 + lm;
#pragma unroll
    for (int e = 0; e < 8; ++e) {
      const float w = Wc[(size_t)(kt * 32 + ko + e) * 2048 + col];
      w2l[kt][e] = (short)f2b(w - b2f(f2b(w)));
    }
  }
  const float biasv = biases[s * 512 + (g << 7) + jbase + lm];
  const float bcv = bcg[(g << 9) + j0 + lm];
  __syncthreads();

  const u16* w1r = &W1H[((g << 4) + lm) * 200];
  const u16* w2r = &W2H[((g << 4) + lm) * 520];
  const int brow = q * 16 + lm;
  const float* xrow = x + (size_t)brow * (512 * 256) + s * 64;
  const int hbase = brow * 512 + s * 128;
  const int arow_off = ((g << 6) + brow) * 512;

  // phase-3 mapping
  const int p3b = tid >> 4, p3j = tid & 15;
  const int p3ci = (q * 16 + p3b) * 512 + j0 + p3j;
  const size_t obase = (size_t)(q * 16 + p3b) * TSTEPS * 512 + j0 + p3j;
  float creg = 0.f, hprev = 0.f;

  // x prefetch registers for t=0
  float4 xa0, xb0, xa1, xb1;
  {
    const float* xp = xrow;
    xa0 = *(const float4*)(xp + ko);
    xb0 = *(const float4*)(xp + ko + 4);
    xa1 = *(const float4*)(xp + 32 + ko);
    xb1 = *(const float4*)(xp + 32 + ko + 4);
  }

  for (int t = 0; t < TSTEPS; ++t) {
    // ---- phase 0: deferred hidden_seq store; build A-fragments ----
    if (t > 0) __builtin_nontemporal_store(hprev, &out[obase + (size_t)(t - 1) * 512]);
    short8 xh[2], xl[2], hh[4], hl[4];
    split8v(xa0, xb0, xh[0], xl[0]);
    split8v(xa1, xb1, xh[1], xl[1]);
#pragma unroll
    for (int kt = 0; kt < 4; ++kt) {
      hh[kt] = lda_frag(&h_hi[hbase + kt * 32 + ko]);
      hl[kt] = lda_frag(&h_lo[hbase + kt * 32 + ko]);
    }

    // ---- phase 1: stage-1 gate (this wave's) -> act bufs (sc1) ----
    {
      floatx4 accA = {0.f, 0.f, 0.f, 0.f}, accB = {0.f, 0.f, 0.f, 0.f};
      floatx4 accC = {0.f, 0.f, 0.f, 0.f};
#pragma unroll
      for (int kt = 0; kt < 2; ++kt) {
        const short8 bh = ld8(w1r + kt * 32 + ko);
        accA = __builtin_amdgcn_mfma_f32_16x16x32_bf16(xh[kt], bh, accA, 0, 0, 0);
        accB = __builtin_amdgcn_mfma_f32_16x16x32_bf16(xl[kt], bh, accB, 0, 0, 0);
        accC = __builtin_amdgcn_mfma_f32_16x16x32_bf16(xh[kt], w1l[kt], accC, 0, 0, 0);
      }
#pragma unroll
      for (int kt = 0; kt < 4; ++kt) {
        const short8 bh = ld8(w1r + 64 + kt * 32 + ko);
        accA = __builtin_amdgcn_mfma_f32_16x16x32_bf16(hh[kt], bh, accA, 0, 0, 0);
        accB = __builtin_amdgcn_mfma_f32_16x16x32_bf16(hl[kt], bh, accB, 0, 0, 0);
        accC = __builtin_amdgcn_mfma_f32_16x16x32_bf16(hh[kt], w1l[2 + kt], accC, 0, 0, 0);
      }
      const int pp = (t & 1) * ACT_PLANE;
#pragma unroll
      for (int r = 0; r < 4; ++r) {
        const int b = q * 16 + lq * 4 + r;
        const float pre = accA[r] + accB[r] + accC[r] + biasv;
        const float a = (g == 2) ? tanhf_fast(pre) : sigf(pre);
        const u16 ah = f2b(a);
        const int o = pp + ((g << 6) + b) * 512 + j0 + lm;
        sta16(&act_hi[o], ah);
        sta16(&act_lo[o], f2b(a - b2f(ah)));
      }
    }
    barrier_flags(flags1, 31, jt, (unsigned)(t + 1));

    // ---- phase 2: prefetch x(t+1); connector GEMM (acts via L3) ----
    {
      const float* xp = xrow + (t < TSTEPS - 1 ? (t + 1) : t) * 256;
      xa0 = *(const float4*)(xp + ko);
      xb0 = *(const float4*)(xp + ko + 4);
      xa1 = *(const float4*)(xp + 32 + ko);
      xb1 = *(const float4*)(xp + 32 + ko + 4);
    }
    floatx4 a2a = {0.f, 0.f, 0.f, 0.f}, a2b = {0.f, 0.f, 0.f, 0.f};
    floatx4 a2c = {0.f, 0.f, 0.f, 0.f}, a2d = {0.f, 0.f, 0.f, 0.f};
    {
      const u16* ah = act_hi + (t & 1) * ACT_PLANE + arow_off;
      const u16* al = act_lo + (t & 1) * ACT_PLANE + arow_off;
#pragma unroll
      for (int kt = 0; kt < 16; kt += 2) {
        const int kb0 = kt * 32 + ko, kb1 = (kt + 1) * 32 + ko;
        const short8 Ah0 = lda_frag(ah + kb0), Al0 = lda_frag(al + kb0);
        const short8 Ah1 = lda_frag(ah + kb1), Al1 = lda_frag(al + kb1);
        const short8 Bh0 = ld8(w2r + kb0), Bh1 = ld8(w2r + kb1);
        a2a = __builtin_amdgcn_mfma_f32_16x16x32_bf16(Ah0, Bh0, a2a, 0, 0, 0);
        a2b = __builtin_amdgcn_mfma_f32_16x16x32_bf16(Al0, Bh0, a2b, 0, 0, 0);
        a2c = __builtin_amdgcn_mfma_f32_16x16x32_bf16(Ah0, w2l[kt], a2c, 0, 0, 0);
        a2d = __builtin_amdgcn_mfma_f32_16x16x32_bf16(Ah1, Bh1, a2d, 0, 0, 0);
        a2a = __builtin_amdgcn_mfma_f32_16x16x32_bf16(Al1, Bh1, a2a, 0, 0, 0);
        a2b = __builtin_amdgcn_mfma_f32_16x16x32_bf16(Ah1, w2l[kt + 1], a2b, 0, 0, 0);
      }
    }
#pragma unroll
    for (int r = 0; r < 4; ++r)
      gx[g][lq * 4 + r][lm] = (a2a[r] + a2b[r]) + (a2c[r] + a2d[r]) + bcv;
    __syncthreads();

    // ---- phase 3: elementwise update; h stores (sc1) ----
    {
      const float it = sigf(gx[0][p3b][p3j]);
      const float ft = sigf(gx[1][p3b][p3j]);
      const float gt = tanhf_fast(gx[2][p3b][p3j]);
      const float ot = sigf(gx[3][p3b][p3j]);
      const float cn = ft * creg + it * gt;
      creg = cn;
      const float h = ot * tanhf_fast(cn);
      hprev = h;
      if (t < TSTEPS - 1) {
        const u16 hh2 = f2b(h);
        sta16(&h_hi[p3ci], hh2);
        sta16(&h_lo[p3ci], f2b(h - b2f(hh2)));
      } else {
        __builtin_nontemporal_store(h, &out[obase + (size_t)t * 512]);
        __builtin_nontemporal_store(h, &out[16777216 + p3ci]);
        __builtin_nontemporal_store(cn, &out[16777216 + 32768 + p3ci]);
      }
    }
    if (t < TSTEPS - 1) barrier_flags(flags2, 7, jt & 7, (unsigned)(t + 1));
  }
}

extern "C" void kernel_launch(void* const* d_in, const int* in_sizes, int n_in,
                              void* d_out, int out_size, void* d_ws, size_t ws_size,
                              hipStream_t stream) {
  const float* x = (const float*)d_in[0];
  const float* Ws = (const float*)d_in[1];
  const float* Us = (const float*)d_in[2];
  const float* biases = (const float*)d_in[3];
  const float* Wc = (const float*)d_in[4];
  const float* bc = (const float*)d_in[5];

  char* ws = (char*)d_ws;
  unsigned* flagbase = (unsigned*)(ws + WS_FLAG1);
  u16* h_hi = (u16*)(ws + WS_H_HI);
  u16* h_lo = (u16*)(ws + WS_H_LO);
  u16* act_hi = (u16*)(ws + WS_ACT_HI);
  u16* act_lo = (u16*)(ws + WS_ACT_LO);

  hipLaunchKernelGGL(init_ws_kernel, dim3(64), dim3(NT), 0, stream, (unsigned*)ws,
                     WS_ZERO_BYTES / 4);
  hipLaunchKernelGGL(slicelstm_kernel, dim3(NBLK), dim3(NT), 0, stream, x, Ws, Us,
                     biases, Wc, bc, (float*)d_out, act_hi, act_lo, h_hi, h_lo, flagbase);
}